// Round 6
// baseline (138.502 us; speedup 1.0000x reference)
//
#include <hip/hip_runtime.h>
#include <hip/hip_bf16.h>

// CrossViewContrast: loss = -mean_i( 2*<z1n_i,z2n_i> - log(sum_j exp(2*<z1n_i,z2n_j>) + 1e-8) )
// N=16384, D=128. bf16 MFMA GEMM with exp2 rowsum epilogue; sim never materialized.
// R2: 2*log2e baked into z1n -> epilogue exp2+add. sim 96->76us.
// R3/R4: dbuf prefetch + occupancy push ~neutral: pipes phase-locked serial
//   (matrix 28 + VALU 33 + LDS 10 == wall 72us).
// R5: coop-fused kernel FAILED to launch (all-zero out) -> reverted; two changes
//   at once taught nothing about the ILP theory.
// R6: R4 structure + in-wave exp2-shadow pipeline ONLY: flush tile t-1's
//   accumulator (pacc carry, seeded -1e30) between tile t's MFMA issues so
//   v_exp runs in the matrix-pipe shadow of the SAME wave. Loss kernel widened
//   to 64 blocks + atomicAdd (out zeroed by norm_kernel; stream-ordered).

#define N_ROWS 16384
#define DIM 128
#define JSPLIT 16
#define COLS_PER_BLOCK (N_ROWS / JSPLIT)   // 1024
#define JCHUNK 32
#define NCHUNK (COLS_PER_BLOCK / JCHUNK)   // 32
#define GRANULES (JCHUNK * 16)             // 512 16B-granules per buffer (8 KB)
#define ROWS_PER_BLOCK 128
#define ITILES (N_ROWS / ROWS_PER_BLOCK)   // 128

// exp(2*sim) = 2^(SCALE*sim); SCALE baked into z1n so MFMA acc is already in log2 domain.
#define SCALE 2.8853900817779268f  // 2 * log2(e)

typedef __attribute__((ext_vector_type(8))) short short8;   // 8 bf16 = 4 VGPRs (MFMA A/B frag)
typedef __attribute__((ext_vector_type(4))) float floatx4;  // MFMA C/D frag

#if __has_builtin(__builtin_amdgcn_exp2f)
#define EXP2(x) __builtin_amdgcn_exp2f(x)
#else
#define EXP2(x) exp2f(x)
#endif

__device__ inline void gload_lds16(const void* gptr, void* lptr) {
  __builtin_amdgcn_global_load_lds(
      (const __attribute__((address_space(1))) void*)gptr,
      (__attribute__((address_space(3))) void*)lptr, 16, 0, 0);
}

// ---------------- Kernel 1: row norms + diagonal + bf16 cast + zero init ----
__global__ __launch_bounds__(256) void norm_kernel(
    const float* __restrict__ z1, const float* __restrict__ z2,
    __hip_bfloat16* __restrict__ z1n, __hip_bfloat16* __restrict__ z2n,
    float* __restrict__ diag, float* __restrict__ denom,
    float* __restrict__ out) {
  int tid = threadIdx.x;
  int wave = tid >> 6, lane = tid & 63;
  int row = blockIdx.x * 4 + wave;   // one wave per row
  const float2* p1 = (const float2*)(z1 + (size_t)row * DIM);
  const float2* p2 = (const float2*)(z2 + (size_t)row * DIM);
  float2 a = p1[lane], b = p2[lane];
  float s11 = a.x * a.x + a.y * a.y;
  float s22 = b.x * b.x + b.y * b.y;
  float s12 = a.x * b.x + a.y * b.y;
#pragma unroll
  for (int m = 32; m >= 1; m >>= 1) {
    s11 += __shfl_xor(s11, m);
    s22 += __shfl_xor(s22, m);
    s12 += __shfl_xor(s12, m);
  }
  float inv1 = 1.0f / fmaxf(sqrtf(s11), 1e-12f);  // torch F.normalize eps
  float inv2 = 1.0f / fmaxf(sqrtf(s22), 1e-12f);
  float sc1 = inv1 * SCALE;                        // bake exp scale into A
  __hip_bfloat162 o1, o2;
  o1.x = __float2bfloat16(a.x * sc1);  o1.y = __float2bfloat16(a.y * sc1);
  o2.x = __float2bfloat16(b.x * inv2); o2.y = __float2bfloat16(b.y * inv2);
  ((__hip_bfloat162*)(z1n + (size_t)row * DIM))[lane] = o1;
  ((__hip_bfloat162*)(z2n + (size_t)row * DIM))[lane] = o2;
  if (lane == 0) {
    diag[row]  = s12 * inv1 * inv2;  // exact fp32 diagonal
    denom[row] = 0.0f;
  }
  if (blockIdx.x == 0 && tid == 0) out[0] = 0.0f;
}

// ---------------- Kernel 2: denom_i += sum_j exp(2*sim_ij), bf16 MFMA -------
// R4 structure (32 rows/wave, 8KB dbuf chunks, XOR-swizzle -> 0 conflicts)
// + in-wave software pipeline: EXP2-flush of the previous 16x16 tile issued
// between the current tile's MFMAs (same-wave ILP overlap of trans & matrix).
__global__ __launch_bounds__(256, 6) void sim_kernel(
    const __hip_bfloat16* __restrict__ z1n,
    const __hip_bfloat16* __restrict__ z2n,
    float* __restrict__ denom) {
  __shared__ short8 lds8[2][GRANULES];  // 2 x 8 KB

  int tid = threadIdx.x;
  int w   = tid >> 6;
  int q   = (tid >> 4) & 3;   // quad within wave
  int l15 = tid & 15;
  int itile  = blockIdx.x & (ITILES - 1);
  int jsplit = blockIdx.x >> 7;
  int i0 = itile * ROWS_PER_BLOCK + w * 32;

  // A fragments: 2 i-subtiles x 4 k-chunks. A[m=lane&15][k=quad*8+j].
  short8 afrag[2][4];
  const short* A = (const short*)z1n;
#pragma unroll
  for (int ii = 0; ii < 2; ++ii) {
    const short* rp = A + (size_t)(i0 + ii * 16 + l15) * DIM;
#pragma unroll
    for (int kk = 0; kk < 4; ++kk)
      afrag[ii][kk] = *(const short8*)(rp + q * 8 + kk * 32);
  }

  // precomputed LDS granule indices (jj adds a compile-time 256)
  int bidx[4];
#pragma unroll
  for (int kk = 0; kk < 4; ++kk) bidx[kk] = l15 * 16 + ((q + 4 * kk) ^ l15);

  floatx4 rowsum[2];
  rowsum[0] = (floatx4){0.f, 0.f, 0.f, 0.f};
  rowsum[1] = (floatx4){0.f, 0.f, 0.f, 0.f};
  // carried accumulator; seed -1e30 so the very first flush adds exp2(-1e30)=0
  floatx4 pacc = (floatx4){-1e30f, -1e30f, -1e30f, -1e30f};

  const char* Bbase = (const char*)z2n + (size_t)jsplit * COLS_PER_BLOCK * (DIM * 2);

#define STAGE(cidx, bufi)                                                    \
  do {                                                                       \
    const char* _ck = Bbase + (size_t)(cidx) * JCHUNK * 256;                 \
    char* _dst = (char*)&lds8[bufi][0];                                      \
    _Pragma("unroll")                                                        \
    for (int _r = 0; _r < 2; ++_r) {                                         \
      int _G = _r * 256 + tid;                                               \
      int _rowl = _G >> 4, _gl = _G & 15;                                    \
      int _gsrc = _gl ^ (_rowl & 15);                                        \
      gload_lds16(_ck + (size_t)_rowl * 256 + _gsrc * 16,                    \
                  _dst + (size_t)_G * 16);                                   \
    }                                                                        \
  } while (0)

  STAGE(0, 0);
  __syncthreads();

  for (int c = 0; c < NCHUNK; ++c) {
    if (c + 1 < NCHUNK) STAGE(c + 1, (c + 1) & 1);
    const short8* buf = &lds8[c & 1][0];

#pragma unroll
    for (int jj = 0; jj < 2; ++jj) {
      short8 bfr[4];
#pragma unroll
      for (int kk = 0; kk < 4; ++kk) bfr[kk] = buf[jj * 256 + bidx[kk]];

      // tile (jj, ii=0): issue MFMAs, flush PREVIOUS tile (ii=1 parity) in shadow
      {
        floatx4 nacc = (floatx4){0.f, 0.f, 0.f, 0.f};
#pragma unroll
        for (int kk = 0; kk < 4; ++kk)
          nacc = __builtin_amdgcn_mfma_f32_16x16x32_bf16(afrag[0][kk], bfr[kk], nacc, 0, 0, 0);
        floatx4 e;
#pragma unroll
        for (int r = 0; r < 4; ++r) e[r] = EXP2(pacc[r]);
        rowsum[1] += e;
        pacc = nacc;
      }
      // tile (jj, ii=1): issue MFMAs, flush previous tile (ii=0 parity) in shadow
      {
        floatx4 nacc = (floatx4){0.f, 0.f, 0.f, 0.f};
#pragma unroll
        for (int kk = 0; kk < 4; ++kk)
          nacc = __builtin_amdgcn_mfma_f32_16x16x32_bf16(afrag[1][kk], bfr[kk], nacc, 0, 0, 0);
        floatx4 e;
#pragma unroll
        for (int r = 0; r < 4; ++r) e[r] = EXP2(pacc[r]);
        rowsum[0] += e;
        pacc = nacc;
      }
    }
    __syncthreads();  // guards buf reuse; acc regs unaffected
  }
  // final flush: pacc holds the last tile (ii=1)
  {
    floatx4 e;
#pragma unroll
    for (int r = 0; r < 4; ++r) e[r] = EXP2(pacc[r]);
    rowsum[1] += e;
  }

  // reduce the 16 column-partials (spread over l15) and commit
#pragma unroll
  for (int ii = 0; ii < 2; ++ii)
#pragma unroll
    for (int r = 0; r < 4; ++r) {
      float v = rowsum[ii][r];
      v += __shfl_xor(v, 1);
      v += __shfl_xor(v, 2);
      v += __shfl_xor(v, 4);
      v += __shfl_xor(v, 8);
      if (l15 == 0) atomicAdd(&denom[i0 + ii * 16 + q * 4 + r], v);
    }
}

// ---------------- Kernel 3: loss = -mean(2*diag - log(denom+eps)) -----------
// 64 blocks x 256 threads; one row/thread; wave-reduce then one atomicAdd/wave.
__global__ __launch_bounds__(256) void loss_kernel(
    const float* __restrict__ denom, const float* __restrict__ diag,
    float* __restrict__ out) {
  int row = blockIdx.x * 256 + threadIdx.x;
  float t = 2.0f * diag[row] - __logf(denom[row] + 1e-8f);
#pragma unroll
  for (int m = 32; m >= 1; m >>= 1) t += __shfl_xor(t, m);
  if ((threadIdx.x & 63) == 0) atomicAdd(out, -t * (1.0f / N_ROWS));
}

extern "C" void kernel_launch(void* const* d_in, const int* in_sizes, int n_in,
                              void* d_out, int out_size, void* d_ws, size_t ws_size,
                              hipStream_t stream) {
  const float* z1 = (const float*)d_in[0];
  const float* z2 = (const float*)d_in[1];
  char* ws = (char*)d_ws;
  __hip_bfloat16* z1n = (__hip_bfloat16*)ws;                                   // 4 MB
  __hip_bfloat16* z2n = (__hip_bfloat16*)(ws + (size_t)N_ROWS * DIM * 2);      // 4 MB
  float* denom = (float*)(ws + (size_t)N_ROWS * DIM * 4);                      // 64 KB
  float* diag  = (float*)(ws + (size_t)N_ROWS * DIM * 4 + (size_t)N_ROWS * 4); // 64 KB
  float* outp  = (float*)d_out;

  norm_kernel<<<N_ROWS / 4, 256, 0, stream>>>(z1, z2, z1n, z2n, diag, denom, outp);
  sim_kernel<<<ITILES * JSPLIT, 256, 0, stream>>>(z1n, z2n, denom);
  loss_kernel<<<N_ROWS / 256, 256, 0, stream>>>(denom, diag, outp);
}

// Round 8
// 111.533 us; speedup vs baseline: 1.2418x; 1.2418x over previous
//
#include <hip/hip_runtime.h>
#include <hip/hip_bf16.h>
#include <hip/hip_fp8.h>

// CrossViewContrast: loss = -mean_i( 2*<z1n_i,z2n_i> - log(sum_j exp(2*<z1n_i,z2n_j>) + 1e-8) )
// N=16384, D=128.
// R1-R6: bf16 16x16x32 MFMA GEMM + exp2 rowsum epilogue plateaus at sim ~72us
//   (~950 TF effective = the documented ~36-38% compiler-scheduled plateau).
// R7: MX-fp8 mfma_scale_f32_16x16x128_f8f6f4 (K=128 in ONE instruction, 2x rate),
//   identity e8m0 scales. FAILED TO COMPILE: braced init list inside macro args.
// R8: same kernel, mechanical fix (inline function + named zero vector).

#define N_ROWS 16384
#define DIM 128
#define JSPLIT 16
#define COLS_PER_BLOCK (N_ROWS / JSPLIT)   // 1024
#define JCHUNK 32
#define NCHUNK (COLS_PER_BLOCK / JCHUNK)   // 32
#define ROWS_PER_BLOCK 128
#define ITILES (N_ROWS / ROWS_PER_BLOCK)   // 128

// exp(2*sim) = 2^(SCALE*sim); SCALE baked into z1q so MFMA acc is already log2-domain.
#define SCALE 2.8853900817779268f  // 2 * log2(e)

typedef __attribute__((ext_vector_type(8))) int   int8v;   // v8i32: 32 fp8 bytes (MFMA A/B frag)
typedef __attribute__((ext_vector_type(4))) int   int4v;   // one 16B LDS granule
typedef __attribute__((ext_vector_type(4))) float floatx4; // MFMA C/D frag

#if __has_builtin(__builtin_amdgcn_exp2f)
#define EXP2(x) __builtin_amdgcn_exp2f(x)
#else
#define EXP2(x) exp2f(x)
#endif

// fmt 0 = OCP e4m3 for both A and B; scales = e8m0 1.0 in all bytes (identity).
__device__ inline floatx4 mfma_fp8_k128(int8v a, int8v b, floatx4 c) {
  return __builtin_amdgcn_mfma_scale_f32_16x16x128_f8f6f4(
      a, b, c, 0, 0, 0, 0x7F7F7F7F, 0, 0x7F7F7F7F);
}

__device__ inline void gload_lds16(const void* gptr, void* lptr) {
  __builtin_amdgcn_global_load_lds(
      (const __attribute__((address_space(1))) void*)gptr,
      (__attribute__((address_space(3))) void*)lptr, 16, 0, 0);
}

__device__ inline short pack_fp8x2(float x, float y) {
#if __has_builtin(__builtin_amdgcn_cvt_pk_fp8_f32)
  int p = __builtin_amdgcn_cvt_pk_fp8_f32(x, y, 0, false);  // bytes 0,1 of result
  return (short)(p & 0xFFFF);
#else
  __hip_fp8_e4m3 a(x), b(y);
  return (short)((unsigned char)a.__x | ((unsigned short)(unsigned char)b.__x << 8));
#endif
}

// ---------------- Kernel 1: row norms + diagonal + fp8 cast + zero init -----
__global__ __launch_bounds__(256) void norm_kernel(
    const float* __restrict__ z1, const float* __restrict__ z2,
    unsigned char* __restrict__ z1q, unsigned char* __restrict__ z2q,
    float* __restrict__ diag, float* __restrict__ denom,
    float* __restrict__ out) {
  int tid = threadIdx.x;
  int wave = tid >> 6, lane = tid & 63;
  int row = blockIdx.x * 4 + wave;   // one wave per row
  const float2* p1 = (const float2*)(z1 + (size_t)row * DIM);
  const float2* p2 = (const float2*)(z2 + (size_t)row * DIM);
  float2 a = p1[lane], b = p2[lane];
  float s11 = a.x * a.x + a.y * a.y;
  float s22 = b.x * b.x + b.y * b.y;
  float s12 = a.x * b.x + a.y * b.y;
#pragma unroll
  for (int m = 32; m >= 1; m >>= 1) {
    s11 += __shfl_xor(s11, m);
    s22 += __shfl_xor(s22, m);
    s12 += __shfl_xor(s12, m);
  }
  float inv1 = 1.0f / fmaxf(sqrtf(s11), 1e-12f);  // torch F.normalize eps
  float inv2 = 1.0f / fmaxf(sqrtf(s22), 1e-12f);
  float sc1 = inv1 * SCALE;                        // bake exp scale into A side
  // fp8 e4m3 (OCP on gfx950): |z1q| <= SCALE ~ 2.89 << 448 max. k order: 2*lane, 2*lane+1.
  ((short*)(z1q + (size_t)row * DIM))[lane] = pack_fp8x2(a.x * sc1, a.y * sc1);
  ((short*)(z2q + (size_t)row * DIM))[lane] = pack_fp8x2(b.x * inv2, b.y * inv2);
  if (lane == 0) {
    diag[row]  = s12 * inv1 * inv2;  // exact fp32 diagonal
    denom[row] = 0.0f;
  }
  if (blockIdx.x == 0 && tid == 0) out[0] = 0.0f;
}

// ---------------- Kernel 2: denom_i += sum_j exp(2*sim_ij), MX-fp8 MFMA -----
// Block: 4 waves; wave w owns rows [i0+w*32,+32). B chunk: 32 cols x 128 B fp8
// = 4 KB, double-buffered (8 KB LDS). Rows have 8 16B-granules; XOR-swizzle
// granule by (row&7): read phase-groups get exactly 8 lanes each -> conflict-free.
// One K=128 MFMA per 16x16 tile; exp2-flush of previous tile in its shadow.
__global__ __launch_bounds__(256, 8) void sim_kernel(
    const unsigned char* __restrict__ z1q,
    const unsigned char* __restrict__ z2q,
    float* __restrict__ denom) {
  __shared__ int4v lds[2][JCHUNK * 8];  // 2 x 4 KB

  int tid = threadIdx.x;
  int w   = tid >> 6;
  int q   = (tid >> 4) & 3;   // quad within wave
  int l15 = tid & 15;
  int s   = l15 & 7;          // read-side swizzle key
  int itile  = blockIdx.x & (ITILES - 1);
  int jsplit = blockIdx.x >> 7;
  int i0 = itile * ROWS_PER_BLOCK + w * 32;

  const floatx4 ZERO4 = {0.f, 0.f, 0.f, 0.f};

  // A fragments: lane (q,l15) holds bytes [q*32, q*32+32) of row (i0+ii*16+l15).
  int8v afrag[2];
#pragma unroll
  for (int ii = 0; ii < 2; ++ii) {
    const int4v* rp = (const int4v*)(z1q + (size_t)(i0 + ii * 16 + l15) * DIM);
    int4v a0 = rp[q * 2], a1 = rp[q * 2 + 1];
    int8v af;
    af[0] = a0[0]; af[1] = a0[1]; af[2] = a0[2]; af[3] = a0[3];
    af[4] = a1[0]; af[5] = a1[1]; af[6] = a1[2]; af[7] = a1[3];
    afrag[ii] = af;
  }

  floatx4 rowsum[2];
  rowsum[0] = ZERO4;
  rowsum[1] = ZERO4;
  // carried accumulator; seed -1e30 so the first flush adds exp2(-1e30) = 0
  floatx4 pacc = {-1e30f, -1e30f, -1e30f, -1e30f};
  int psel = 1;  // which rowsum the pending pacc belongs to

  const char* Bbase = (const char*)z2q + (size_t)jsplit * COLS_PER_BLOCK * DIM;

  // stage one 4 KB chunk: 256 thr x 16 B. LDS dest lane-linear (global_load_lds
  // constraint); XOR swizzle applied to the GLOBAL source granule.
#define STAGE(cidx, bufi)                                                    \
  do {                                                                       \
    const char* _ck = Bbase + (size_t)(cidx) * JCHUNK * DIM;                 \
    char* _dst = (char*)&lds[bufi][0];                                       \
    int _row = tid >> 3, _gl = tid & 7;                                      \
    int _gsrc = _gl ^ (_row & 7);                                            \
    gload_lds16(_ck + (size_t)_row * DIM + _gsrc * 16,                       \
                _dst + (size_t)tid * 16);                                    \
  } while (0)

  STAGE(0, 0);
  __syncthreads();

  for (int c = 0; c < NCHUNK; ++c) {
    if (c + 1 < NCHUNK) STAGE(c + 1, (c + 1) & 1);
    const int4v* buf = &lds[c & 1][0];

#pragma unroll
    for (int jj = 0; jj < 2; ++jj) {
      int rbase = (jj * 16 + l15) * 8;
      int4v lo = buf[rbase + ((2 * q) ^ s)];
      int4v hi = buf[rbase + ((2 * q + 1) ^ s)];
      int8v bf;
      bf[0] = lo[0]; bf[1] = lo[1]; bf[2] = lo[2]; bf[3] = lo[3];
      bf[4] = hi[0]; bf[5] = hi[1]; bf[6] = hi[2]; bf[7] = hi[3];

#pragma unroll
      for (int ii = 0; ii < 2; ++ii) {
        floatx4 nacc = mfma_fp8_k128(afrag[ii], bf, ZERO4);
        // flush the PREVIOUS tile's accumulator in this MFMA's shadow
        floatx4 e;
#pragma unroll
        for (int r = 0; r < 4; ++r) e[r] = EXP2(pacc[r]);
        rowsum[psel] += e;
        pacc = nacc;
        psel = ii;
      }
    }
    __syncthreads();  // guards buf reuse
  }
  // final flush
  {
    floatx4 e;
#pragma unroll
    for (int r = 0; r < 4; ++r) e[r] = EXP2(pacc[r]);
    rowsum[psel] += e;
  }

  // reduce the 16 column-partials (spread over l15) and commit.
  // C/D layout (shape-determined): col = lane&15 (j), row = q*4 + r (i).
#pragma unroll
  for (int ii = 0; ii < 2; ++ii)
#pragma unroll
    for (int r = 0; r < 4; ++r) {
      float v = rowsum[ii][r];
      v += __shfl_xor(v, 1);
      v += __shfl_xor(v, 2);
      v += __shfl_xor(v, 4);
      v += __shfl_xor(v, 8);
      if (l15 == 0) atomicAdd(&denom[i0 + ii * 16 + q * 4 + r], v);
    }
}

// ---------------- Kernel 3: loss = -mean(2*diag - log(denom+eps)) -----------
// 64 blocks x 256 threads; one row/thread; wave-reduce then one atomicAdd/wave.
__global__ __launch_bounds__(256) void loss_kernel(
    const float* __restrict__ denom, const float* __restrict__ diag,
    float* __restrict__ out) {
  int row = blockIdx.x * 256 + threadIdx.x;
  float t = 2.0f * diag[row] - __logf(denom[row] + 1e-8f);
#pragma unroll
  for (int m = 32; m >= 1; m >>= 1) t += __shfl_xor(t, m);
  if ((threadIdx.x & 63) == 0) atomicAdd(out, -t * (1.0f / N_ROWS));
}

extern "C" void kernel_launch(void* const* d_in, const int* in_sizes, int n_in,
                              void* d_out, int out_size, void* d_ws, size_t ws_size,
                              hipStream_t stream) {
  const float* z1 = (const float*)d_in[0];
  const float* z2 = (const float*)d_in[1];
  char* ws = (char*)d_ws;
  unsigned char* z1q = (unsigned char*)ws;                                  // 2 MB
  unsigned char* z2q = (unsigned char*)(ws + (size_t)N_ROWS * DIM);         // 2 MB
  float* denom = (float*)(ws + (size_t)2 * N_ROWS * DIM);                   // 64 KB
  float* diag  = (float*)(ws + (size_t)2 * N_ROWS * DIM + (size_t)N_ROWS * 4);
  float* outp  = (float*)d_out;

  norm_kernel<<<N_ROWS / 4, 256, 0, stream>>>(z1, z2, z1q, z2q, diag, denom, outp);
  sim_kernel<<<ITILES * JSPLIT, 256, 0, stream>>>(z1q, z2q, denom);
  loss_kernel<<<N_ROWS / 256, 256, 0, stream>>>(denom, diag, outp);
}